// Round 7
// baseline (89.545 us; speedup 1.0000x reference)
//
#include <hip/hip_runtime.h>
#include <math.h>

// ============================================================================
// MEASUREMENT ROUND: exact round-4 kernels; kA launched TWICE (idempotent) so
// dur_us = 2*kA + kB + 2*boundary. With round-4's kA+kB+boundary = 57.6 us,
// this yields kA directly: kA = dur_us - 57.6 - ~3.5.
// ============================================================================

#define HDIM 512
#define NROWS 100000
#define NBLK_A 2048
#define NBLK_B 64

// ---- workspace layout (float indices) ----
constexpr int SIMS_OFF   = 0;                        // [NROWS] sims = -||K-cue||^2
constexpr int BMIN_OFF   = NROWS;                    // [NBLK_A] per-block min ||K-cue||^2
constexpr int CNT_OFF    = BMIN_OFF + NBLK_A;        // [1] int ticket counter
constexpr int PREACT_OFF = CNT_OFF + 1;              // [5*HDIM]
constexpr int PM_OFF     = PREACT_OFF + 5 * HDIM;    // [NBLK_B*HDIM] partial e*V
constexpr int PD_OFF     = PM_OFF + NBLK_B * HDIM;   // [NBLK_B] partial e

__device__ __forceinline__ float wave_sum(float v) {
    #pragma unroll
    for (int off = 32; off; off >>= 1) v += __shfl_xor(v, off);
    return v;
}
__device__ __forceinline__ float wave_min(float v) {
    #pragma unroll
    for (int off = 32; off; off >>= 1) v = fminf(v, __shfl_xor(v, off));
    return v;
}
__device__ __forceinline__ float d2sum(float4 a, float4 c) {
    float d, s;
    d = a.x - c.x; s  = d * d;
    d = a.y - c.y; s += d * d;
    d = a.z - c.z; s += d * d;
    d = a.w - c.w; s += d * d;
    return s;
}

// ================= kernel A: preact + sims sweep + per-block min =============
__global__ __launch_bounds__(256)
void kA(const float* __restrict__ state, const float* __restrict__ pa,
        const float* __restrict__ pr, const float* __restrict__ ts,
        const float* __restrict__ cue, const float* __restrict__ K,
        const float* __restrict__ Wx, const float* __restrict__ Wh,
        const float* __restrict__ b, const float* __restrict__ h0,
        float* __restrict__ ws) {
    if (blockIdx.x == 0 && threadIdx.x == 0)
        ((int*)ws)[CNT_OFF] = 0;   // ticket for kernel B (stream-ordered: B after A)

    const int lane = threadIdx.x & 63;
    const int wib  = threadIdx.x >> 6;
    const int gw   = blockIdx.x * 4 + wib;
    const int nw   = NBLK_A * 4;                 // 8192 waves

    // ---- preact rows (first 2560 waves; hides under the BW-bound sweep) ----
    if (gw < 5 * HDIM) {
        const int row = gw;
        float x0 = state[lane];
        float x1 = 0.f;
        if      (lane < 4)  x1 = pa[lane];
        else if (lane == 4) x1 = pr[0];
        else if (lane == 5) x1 = ts[0];

        const float4* h04 = (const float4*)h0;
        const float4  hA = h04[lane], hB = h04[64 + lane];
        const float4* wh4 = (const float4*)(Wh + (size_t)row * HDIM);
        const float4 a0 = wh4[lane], a1 = wh4[64 + lane];
        float acc = a0.x*hA.x + a0.y*hA.y + a0.z*hA.z + a0.w*hA.w
                  + a1.x*hB.x + a1.y*hB.y + a1.z*hB.z + a1.w*hB.w;
        const float* wxr = Wx + (size_t)row * 70;
        acc += wxr[lane] * x0;
        if (lane < 6) acc += wxr[64 + lane] * x1;
        acc = wave_sum(acc);
        if (lane == 0) ws[PREACT_OFF + row] = acc + b[row];
    }

    // ---- sims sweep: 4-row groups, 8 dwordx4 loads in flight, ILP'd reduce --
    const float4* c4 = (const float4*)cue;
    const float4 cA = c4[lane], cB = c4[64 + lane];
    float minss = INFINITY;

    const int NG = NROWS / 4;                    // 25000 groups (NROWS % 4 == 0)
    for (int g = gw; g < NG; g += nw) {
        const int n = g * 4;                     // rows n..n+3
        const float* r = K + (size_t)n * HDIM;
        const float4* p0 = (const float4*)(r);
        const float4* p1 = (const float4*)(r + HDIM);
        const float4* p2 = (const float4*)(r + 2 * HDIM);
        const float4* p3 = (const float4*)(r + 3 * HDIM);
        const float4 a0 = p0[lane], b0 = p0[64 + lane];
        const float4 a1 = p1[lane], b1 = p1[64 + lane];
        const float4 a2 = p2[lane], b2 = p2[64 + lane];
        const float4 a3 = p3[lane], b3 = p3[64 + lane];
        float s0 = d2sum(a0, cA) + d2sum(b0, cB);
        float s1 = d2sum(a1, cA) + d2sum(b1, cB);
        float s2 = d2sum(a2, cA) + d2sum(b2, cB);
        float s3 = d2sum(a3, cA) + d2sum(b3, cB);
        #pragma unroll
        for (int off = 32; off; off >>= 1) {     // 4 independent chains, ILP
            s0 += __shfl_xor(s0, off);
            s1 += __shfl_xor(s1, off);
            s2 += __shfl_xor(s2, off);
            s3 += __shfl_xor(s3, off);
        }
        if (lane == 0) {                         // n%4==0 -> 16B aligned
            *(float4*)&ws[SIMS_OFF + n] = make_float4(-s0, -s1, -s2, -s3);
        }
        minss = fminf(fminf(minss, s0), fminf(fminf(s1, s2), s3));
    }

    minss = wave_min(minss);
    __shared__ float smin[4];
    if (lane == 0) smin[wib] = minss;
    __syncthreads();
    if (threadIdx.x == 0)
        ws[BMIN_OFF + blockIdx.x] =
            fminf(fminf(smin[0], smin[1]), fminf(smin[2], smin[3]));
}

// ====== kernel B: global max + gather + partials + ticketed final ============
__global__ __launch_bounds__(256)
void kB(const float* __restrict__ V, const float* __restrict__ c0,
        const float* __restrict__ aw, const float* __restrict__ ab,
        const float* __restrict__ cw, const float* __restrict__ cb,
        float* __restrict__ ws, float* __restrict__ out) {
    const int lane = threadIdx.x & 63;
    const int wib  = threadIdx.x >> 6;
    const int t    = threadIdx.x;

    // ---- every block computes the identical global max (deterministic) ----
    float mn = INFINITY;
    #pragma unroll
    for (int i = 0; i < NBLK_A / 256; i++)
        mn = fminf(mn, ws[BMIN_OFF + i * 256 + t]);
    mn = wave_min(mn);
    __shared__ float sred[4];
    if (lane == 0) sred[wib] = mn;
    __syncthreads();
    const float smax = -fminf(fminf(sred[0], sred[1]), fminf(sred[2], sred[3]));

    // ---- gather surviving V rows ----
    const int gwid = blockIdx.x * 4 + wib;        // 256 gather waves
    float4 accA = {0.f,0.f,0.f,0.f}, accB = {0.f,0.f,0.f,0.f};
    float dsum = 0.f;

    const int nchunks = (NROWS + 63) / 64;
    for (int c = gwid; c < nchunks; c += NBLK_B * 4) {
        const int n = c * 64 + lane;
        const bool valid = (n < NROWS);
        const float s = valid ? ws[SIMS_OFF + n] : -INFINITY;
        const float e = expf(s - smax);          // underflows to 0 for far rows
        dsum += e;                                // exact denominator
        unsigned long long mask = __ballot(valid && (s - smax >= -30.0f));
        while (mask) {
            const int bpos = __ffsll(mask) - 1;
            mask &= mask - 1;
            const int nb = c * 64 + bpos;
            const float eb = __shfl(e, bpos);
            const float4* v4 = (const float4*)(V + (size_t)nb * HDIM);
            const float4 vA = v4[lane], vB = v4[64 + lane];
            accA.x += eb * vA.x; accA.y += eb * vA.y;
            accA.z += eb * vA.z; accA.w += eb * vA.w;
            accB.x += eb * vB.x; accB.y += eb * vB.y;
            accB.z += eb * vB.z; accB.w += eb * vB.w;
        }
    }
    dsum = wave_sum(dsum);

    __shared__ float lm[4][HDIM];
    __shared__ float ld[4];
    {
        float* rowp = lm[wib];
        rowp[lane*4 + 0]       = accA.x; rowp[lane*4 + 1]       = accA.y;
        rowp[lane*4 + 2]       = accA.z; rowp[lane*4 + 3]       = accA.w;
        rowp[256 + lane*4 + 0] = accB.x; rowp[256 + lane*4 + 1] = accB.y;
        rowp[256 + lane*4 + 2] = accB.z; rowp[256 + lane*4 + 3] = accB.w;
        if (lane == 0) ld[wib] = dsum;
    }
    __syncthreads();

    ws[PM_OFF + blockIdx.x * HDIM + t] =
        lm[0][t] + lm[1][t] + lm[2][t] + lm[3][t];
    ws[PM_OFF + blockIdx.x * HDIM + 256 + t] =
        lm[0][256+t] + lm[1][256+t] + lm[2][256+t] + lm[3][256+t];
    if (t == 0)
        ws[PD_OFF + blockIdx.x] = ld[0] + ld[1] + ld[2] + ld[3];

    // ---- ticket: last block to finish does the final reduce + cell + heads --
    __threadfence();                              // release partials (device scope)
    __shared__ int sOld;
    if (t == 0) sOld = atomicAdd((int*)ws + CNT_OFF, 1);
    __syncthreads();
    if (sOld != NBLK_B - 1) return;
    __threadfence();                              // acquire others' partials

    __shared__ float hl[HDIM];
    __shared__ float sden;
    __shared__ float logits[4];

    if (wib == 0) {
        float d = ws[PD_OFF + lane];              // 64 partials, one per lane
        d = wave_sum(d);
        if (lane == 0) sden = d;
    }
    float m0 = 0.f, m1 = 0.f;
    #pragma unroll 8
    for (int b2 = 0; b2 < NBLK_B; b2++) {
        m0 += ws[PM_OFF + b2 * HDIM + t];
        m1 += ws[PM_OFF + b2 * HDIM + 256 + t];
    }
    __syncthreads();
    const float inv_den = 1.f / sden;
    m0 *= inv_den; m1 *= inv_den;

    #pragma unroll
    for (int half = 0; half < 2; half++) {
        const int tt = t + half * 256;
        const float mm = half ? m1 : m0;
        const float pf = ws[PREACT_OFF + tt];
        const float pi = ws[PREACT_OFF + HDIM + tt];
        const float po = ws[PREACT_OFF + 2*HDIM + tt];
        const float prg= ws[PREACT_OFF + 3*HDIM + tt];
        const float pc = ws[PREACT_OFF + 4*HDIM + tt];
        const float f_t = 1.f / (1.f + expf(-pf));
        const float i_t = 1.f / (1.f + expf(-pi));
        const float o_t = 1.f / (1.f + expf(-po));
        const float r_t = 1.f / (1.f + expf(-prg));
        const float chat = tanhf(pc);
        const float ct = f_t * c0[tt] + i_t * chat + r_t * mm;
        const float ht = o_t * tanhf(ct);
        out[517 + tt] = ct;
        out[5 + tt]   = ht;
        hl[tt] = ht;
    }
    __syncthreads();

    if (wib < 4) {       // actor logits, one wave per row
        float acc = 0.f;
        #pragma unroll
        for (int j = 0; j < HDIM; j += 64)
            acc += aw[wib * HDIM + j + lane] * hl[j + lane];
        acc = wave_sum(acc);
        if (lane == 0) logits[wib] = acc + ab[wib];
    }
    if (wib == 0) {      // critic
        float acc = 0.f;
        #pragma unroll
        for (int j = 0; j < HDIM; j += 64)
            acc += cw[j + lane] * hl[j + lane];
        acc = wave_sum(acc);
        if (lane == 0) out[4] = acc + cb[0];
    }
    __syncthreads();

    if (t == 0) {
        const float mx = fmaxf(fmaxf(logits[0], logits[1]),
                               fmaxf(logits[2], logits[3]));
        const float e0 = expf(logits[0] - mx), e1 = expf(logits[1] - mx);
        const float e2 = expf(logits[2] - mx), e3 = expf(logits[3] - mx);
        const float inv = 1.f / (e0 + e1 + e2 + e3);
        out[0] = e0 * inv; out[1] = e1 * inv;
        out[2] = e2 * inv; out[3] = e3 * inv;
    }
}

extern "C" void kernel_launch(void* const* d_in, const int* in_sizes, int n_in,
                              void* d_out, int out_size, void* d_ws, size_t ws_size,
                              hipStream_t stream) {
    const float* state  = (const float*)d_in[0];
    const float* pa     = (const float*)d_in[1];
    const float* pr     = (const float*)d_in[2];
    const float* ts     = (const float*)d_in[3];
    const float* cue    = (const float*)d_in[4];
    const float* keys   = (const float*)d_in[5];
    const float* vals   = (const float*)d_in[6];
    const float* Wx     = (const float*)d_in[7];
    const float* Wh     = (const float*)d_in[8];
    const float* b      = (const float*)d_in[9];
    const float* aw     = (const float*)d_in[10];
    const float* ab     = (const float*)d_in[11];
    const float* cw     = (const float*)d_in[12];
    const float* cb     = (const float*)d_in[13];
    const float* h0     = (const float*)d_in[14];
    const float* c0     = (const float*)d_in[15];
    float* ws  = (float*)d_ws;
    float* out = (float*)d_out;

    // kA is a pure function of d_in -> idempotent; launched twice ONLY to
    // split dur_us into kA vs kB+boundary (measurement round). Deterministic:
    // same inputs -> same work -> same output every call.
    kA<<<NBLK_A, 256, 0, stream>>>(state, pa, pr, ts, cue, keys, Wx, Wh, b, h0, ws);
    kA<<<NBLK_A, 256, 0, stream>>>(state, pa, pr, ts, cue, keys, Wx, Wh, b, h0, ws);
    kB<<<NBLK_B, 256, 0, stream>>>(vals, c0, aw, ab, cw, cb, ws, out);
}

// Round 8
// 69.952 us; speedup vs baseline: 1.2801x; 1.2801x over previous
//
#include <hip/hip_runtime.h>
#include <math.h>

#define HDIM 512
#define NROWS 100000
#define NBLK_A 2048
#define K_CAP 1024           // max survivors kB holds (data: ~3)

// ---- workspace layout (float indices) ----
constexpr int BMIN_OFF   = 0;                        // [NBLK_A] per-block min ||K-cue||^2
constexpr int CNT_OFF    = NBLK_A;                   // [NBLK_A] int candidate counts
constexpr int CAND_OFF   = 2 * NBLK_A;               // [NBLK_A*64*2] float2 {ss, idx}
constexpr int PREACT_OFF = CAND_OFF + NBLK_A * 128;  // [5*HDIM]
// total ~268800 floats = 1.075 MB (same footprint as round 6, which passed)

__device__ __forceinline__ float wave_sum(float v) {
    #pragma unroll
    for (int off = 32; off; off >>= 1) v += __shfl_xor(v, off);
    return v;
}
__device__ __forceinline__ float wave_min(float v) {
    #pragma unroll
    for (int off = 32; off; off >>= 1) v = fminf(v, __shfl_xor(v, off));
    return v;
}
__device__ __forceinline__ float d2sum(float4 a, float4 c) {
    float d, s;
    d = a.x - c.x; s  = d * d;
    d = a.y - c.y; s += d * d;
    d = a.z - c.z; s += d * d;
    d = a.w - c.w; s += d * d;
    return s;
}

// ================= kernel A: preact + sims sweep + candidate emission ========
__global__ __launch_bounds__(256)
void kA(const float* __restrict__ state, const float* __restrict__ pa,
        const float* __restrict__ pr, const float* __restrict__ ts,
        const float* __restrict__ cue, const float* __restrict__ K,
        const float* __restrict__ Wx, const float* __restrict__ Wh,
        const float* __restrict__ b, const float* __restrict__ h0,
        float* __restrict__ ws) {
    const int lane = threadIdx.x & 63;
    const int wib  = threadIdx.x >> 6;
    const int blk  = blockIdx.x;
    const int gw   = blk * 4 + wib;
    const int nw   = NBLK_A * 4;                 // 8192 waves

    // ---- preact rows (first 2560 waves; hides under the BW-bound sweep) ----
    if (gw < 5 * HDIM) {
        const int row = gw;
        float x0 = state[lane];
        float x1 = 0.f;
        if      (lane < 4)  x1 = pa[lane];
        else if (lane == 4) x1 = pr[0];
        else if (lane == 5) x1 = ts[0];

        const float4* h04 = (const float4*)h0;
        const float4  hA = h04[lane], hB = h04[64 + lane];
        const float4* wh4 = (const float4*)(Wh + (size_t)row * HDIM);
        const float4 a0 = wh4[lane], a1 = wh4[64 + lane];
        float acc = a0.x*hA.x + a0.y*hA.y + a0.z*hA.z + a0.w*hA.w
                  + a1.x*hB.x + a1.y*hB.y + a1.z*hB.z + a1.w*hB.w;
        const float* wxr = Wx + (size_t)row * 70;
        acc += wxr[lane] * x0;
        if (lane < 6) acc += wxr[64 + lane] * x1;
        acc = wave_sum(acc);
        if (lane == 0) ws[PREACT_OFF + row] = acc + b[row];
    }

    // ---- sims sweep: IDENTICAL hot loop to round 4, store -> LDS not global -
    __shared__ float4 ssb[4][4];                 // per-wave sims, <=4 iterations
    __shared__ float  smin4[4];
    __shared__ int    wcnt[4];

    const float4* c4 = (const float4*)cue;
    const float4 cA = c4[lane], cB = c4[64 + lane];
    float minss = INFINITY;

    const int NG = NROWS / 4;                    // 25000 groups
    int it = 0;
    for (int g = gw; g < NG; g += nw, ++it) {    // 3 or 4 iterations
        const int n = g * 4;                     // rows n..n+3
        const float* r = K + (size_t)n * HDIM;
        const float4* p0 = (const float4*)(r);
        const float4* p1 = (const float4*)(r + HDIM);
        const float4* p2 = (const float4*)(r + 2 * HDIM);
        const float4* p3 = (const float4*)(r + 3 * HDIM);
        const float4 a0 = p0[lane], b0 = p0[64 + lane];
        const float4 a1 = p1[lane], b1 = p1[64 + lane];
        const float4 a2 = p2[lane], b2 = p2[64 + lane];
        const float4 a3 = p3[lane], b3 = p3[64 + lane];
        float s0 = d2sum(a0, cA) + d2sum(b0, cB);
        float s1 = d2sum(a1, cA) + d2sum(b1, cB);
        float s2 = d2sum(a2, cA) + d2sum(b2, cB);
        float s3 = d2sum(a3, cA) + d2sum(b3, cB);
        #pragma unroll
        for (int off = 32; off; off >>= 1) {     // 4 independent chains, ILP
            s0 += __shfl_xor(s0, off);
            s1 += __shfl_xor(s1, off);
            s2 += __shfl_xor(s2, off);
            s3 += __shfl_xor(s3, off);
        }
        if (lane == 0) ssb[wib][it] = make_float4(s0, s1, s2, s3);
        minss = fminf(fminf(minss, s0), fminf(fminf(s1, s2), s3));
    }
    const int nit = it;                          // wave-uniform (3 or 4)

    // minss is already wave-uniform (post-reduction values are uniform)
    if (lane == 0) smin4[wib] = minss;
    __syncthreads();
    const float bminv = fminf(fminf(smin4[0], smin4[1]),
                              fminf(smin4[2], smin4[3]));
    if (threadIdx.x == 0) ws[BMIN_OFF + blk] = bminv;
    const float thr = bminv + 30.0f;

    // ---- count candidates per wave (wave-uniform work) ----
    int cnt = 0;
    for (int i = 0; i < nit; i++) {
        const float4 s = ssb[wib][i];
        cnt += (s.x <= thr) + (s.y <= thr) + (s.z <= thr) + (s.w <= thr);
    }
    if (lane == 0) wcnt[wib] = cnt;
    __syncthreads();

    int woff = 0;
    #pragma unroll
    for (int w = 0; w < 4; w++) if (w < wib) woff += wcnt[w];

    // ---- deterministic emission: (wib, iter, slot) order, lane 0 only ----
    if (lane == 0 && cnt > 0) {
        float2* cand = (float2*)(ws + CAND_OFF) + ((size_t)blk << 6);
        int off = woff;
        for (int i = 0; i < nit; i++) {
            const float4 s = ssb[wib][i];
            const int base = (gw + i * nw) * 4;
            if (s.x <= thr) cand[off++] = make_float2(s.x, __int_as_float(base + 0));
            if (s.y <= thr) cand[off++] = make_float2(s.y, __int_as_float(base + 1));
            if (s.z <= thr) cand[off++] = make_float2(s.z, __int_as_float(base + 2));
            if (s.w <= thr) cand[off++] = make_float2(s.w, __int_as_float(base + 3));
        }
    }
    if (threadIdx.x == 0)
        ((int*)ws)[CNT_OFF + blk] = wcnt[0] + wcnt[1] + wcnt[2] + wcnt[3];
}

// ====== kernel B (single block, round-6-proven): min + survivors + cell ======
__global__ __launch_bounds__(256)
void kB(const float* __restrict__ V, const float* __restrict__ c0,
        const float* __restrict__ aw, const float* __restrict__ ab,
        const float* __restrict__ cw, const float* __restrict__ cb,
        float* __restrict__ ws, float* __restrict__ out) {
    const int t    = threadIdx.x;   // 256 threads
    const int lane = t & 63;
    const int wib  = t >> 6;

    __shared__ float sred[4];
    __shared__ int   sc[256];
    __shared__ float surv_s[K_CAP];
    __shared__ int   surv_n[K_CAP];
    __shared__ float sden;
    __shared__ float hl[HDIM];
    __shared__ float logits[4];

    // ---- 1) global min of ||K-cue||^2 ----
    float mn = INFINITY;
    #pragma unroll
    for (int j = 0; j < NBLK_A / 256; j++)
        mn = fminf(mn, ws[BMIN_OFF + j * 256 + t]);
    mn = wave_min(mn);
    if (lane == 0) sred[wib] = mn;
    __syncthreads();
    const float smin = fminf(fminf(sred[0], sred[1]), fminf(sred[2], sred[3]));
    const float thr  = smin + 30.0f;

    // ---- 2) survivor scan over candidate lists (two-pass, deterministic) ----
    const int*    cnt  = (const int*)ws + CNT_OFF;
    const float2* cand = (const float2*)(ws + CAND_OFF);

    int mycnt = 0;
    #pragma unroll
    for (int j = 0; j < NBLK_A / 256; j++) {
        const int bidx = t + j * 256;
        const int c = cnt[bidx];
        for (int e = 0; e < c; e++)
            if (cand[(bidx << 6) + e].x <= thr) mycnt++;
    }
    sc[t] = mycnt;
    __syncthreads();
    for (int d = 1; d < 256; d <<= 1) {          // inclusive Hillis-Steele
        int v = (t >= d) ? sc[t - d] : 0;
        __syncthreads();
        sc[t] += v;
        __syncthreads();
    }
    const int total = sc[255];
    int off = sc[t] - mycnt;
    #pragma unroll
    for (int j = 0; j < NBLK_A / 256; j++) {     // pass 2: identical order
        const int bidx = t + j * 256;
        const int c = cnt[bidx];
        for (int e = 0; e < c; e++) {
            const float2 ce = cand[(bidx << 6) + e];
            if (ce.x <= thr) {
                if (off < K_CAP) {
                    surv_s[off] = ce.x;
                    surv_n[off] = __float_as_int(ce.y);
                }
                off++;
            }
        }
    }
    __syncthreads();
    const int tot = (total < K_CAP) ? total : K_CAP;

    // ---- 3) weights + denominator (serial, deterministic order) ----
    if (t == 0) {
        float den = 0.f;
        for (int i = 0; i < tot; i++) {
            const float e = expf(smin - surv_s[i]);  // = exp(sim - smax)
            surv_s[i] = e;
            den += e;
        }
        sden = den;
    }
    __syncthreads();
    const float inv_den = 1.f / sden;

    // ---- 4) m_t = sum_i w_i * V[n_i] / den  (t owns dims t, t+256) ----
    float m0 = 0.f, m1 = 0.f;
    for (int i = 0; i < tot; i++) {
        const float w = surv_s[i];
        const size_t base = (size_t)surv_n[i] * HDIM;
        m0 += w * V[base + t];
        m1 += w * V[base + 256 + t];
    }
    m0 *= inv_den; m1 *= inv_den;

    // ---- 5) LSTM cell + heads ----
    #pragma unroll
    for (int half = 0; half < 2; half++) {
        const int tt = t + half * 256;
        const float mm = half ? m1 : m0;
        const float pf = ws[PREACT_OFF + tt];
        const float pi = ws[PREACT_OFF + HDIM + tt];
        const float po = ws[PREACT_OFF + 2*HDIM + tt];
        const float prg= ws[PREACT_OFF + 3*HDIM + tt];
        const float pc = ws[PREACT_OFF + 4*HDIM + tt];
        const float f_t = 1.f / (1.f + expf(-pf));
        const float i_t = 1.f / (1.f + expf(-pi));
        const float o_t = 1.f / (1.f + expf(-po));
        const float r_t = 1.f / (1.f + expf(-prg));
        const float chat = tanhf(pc);
        const float ct = f_t * c0[tt] + i_t * chat + r_t * mm;
        const float ht = o_t * tanhf(ct);
        out[517 + tt] = ct;
        out[5 + tt]   = ht;
        hl[tt] = ht;
    }
    __syncthreads();

    if (wib < 4) {       // actor logits, one wave per row
        float acc = 0.f;
        #pragma unroll
        for (int j = 0; j < HDIM; j += 64)
            acc += aw[wib * HDIM + j + lane] * hl[j + lane];
        acc = wave_sum(acc);
        if (lane == 0) logits[wib] = acc + ab[wib];
    }
    if (wib == 0) {      // critic
        float acc = 0.f;
        #pragma unroll
        for (int j = 0; j < HDIM; j += 64)
            acc += cw[j + lane] * hl[j + lane];
        acc = wave_sum(acc);
        if (lane == 0) out[4] = acc + cb[0];
    }
    __syncthreads();

    if (t == 0) {
        const float mx = fmaxf(fmaxf(logits[0], logits[1]),
                               fmaxf(logits[2], logits[3]));
        const float e0 = expf(logits[0] - mx), e1 = expf(logits[1] - mx);
        const float e2 = expf(logits[2] - mx), e3 = expf(logits[3] - mx);
        const float inv = 1.f / (e0 + e1 + e2 + e3);
        out[0] = e0 * inv; out[1] = e1 * inv;
        out[2] = e2 * inv; out[3] = e3 * inv;
    }
}

extern "C" void kernel_launch(void* const* d_in, const int* in_sizes, int n_in,
                              void* d_out, int out_size, void* d_ws, size_t ws_size,
                              hipStream_t stream) {
    const float* state  = (const float*)d_in[0];
    const float* pa     = (const float*)d_in[1];
    const float* pr     = (const float*)d_in[2];
    const float* ts     = (const float*)d_in[3];
    const float* cue    = (const float*)d_in[4];
    const float* keys   = (const float*)d_in[5];
    const float* vals   = (const float*)d_in[6];
    const float* Wx     = (const float*)d_in[7];
    const float* Wh     = (const float*)d_in[8];
    const float* b      = (const float*)d_in[9];
    const float* aw     = (const float*)d_in[10];
    const float* ab     = (const float*)d_in[11];
    const float* cw     = (const float*)d_in[12];
    const float* cb     = (const float*)d_in[13];
    const float* h0     = (const float*)d_in[14];
    const float* c0     = (const float*)d_in[15];
    float* ws  = (float*)d_ws;
    float* out = (float*)d_out;

    kA<<<NBLK_A, 256, 0, stream>>>(state, pa, pr, ts, cue, keys, Wx, Wh, b, h0, ws);
    kB<<<1, 256, 0, stream>>>(vals, c0, aw, ab, cw, cb, ws, out);
}

// Round 9
// 66.845 us; speedup vs baseline: 1.3396x; 1.0465x over previous
//
#include <hip/hip_runtime.h>
#include <math.h>

#define HDIM 512
#define NROWS 100000
#define NBLK_A 2048
#define NBLK_B 64
#define TB_B 1024            // kB threads/block: 16 waves -> latency hiding

// ---- workspace layout (float indices) ----
constexpr int SIMS_OFF   = 0;                        // [NROWS] sims = -||K-cue||^2
constexpr int BMIN_OFF   = NROWS;                    // [NBLK_A] per-block min ||K-cue||^2
constexpr int CNT_OFF    = BMIN_OFF + NBLK_A;        // [1] int ticket counter
constexpr int PREACT_OFF = CNT_OFF + 1;              // [5*HDIM]
constexpr int PM_OFF     = PREACT_OFF + 5 * HDIM;    // [NBLK_B*HDIM] partial e*V
constexpr int PD_OFF     = PM_OFF + NBLK_B * HDIM;   // [NBLK_B] partial e

__device__ __forceinline__ float wave_sum(float v) {
    #pragma unroll
    for (int off = 32; off; off >>= 1) v += __shfl_xor(v, off);
    return v;
}
__device__ __forceinline__ float wave_min(float v) {
    #pragma unroll
    for (int off = 32; off; off >>= 1) v = fminf(v, __shfl_xor(v, off));
    return v;
}
__device__ __forceinline__ float d2sum(float4 a, float4 c) {
    float d, s;
    d = a.x - c.x; s  = d * d;
    d = a.y - c.y; s += d * d;
    d = a.z - c.z; s += d * d;
    d = a.w - c.w; s += d * d;
    return s;
}

// ========== kernel A: BYTE-IDENTICAL to round 4 (HBM-roofline, proven) =======
__global__ __launch_bounds__(256)
void kA(const float* __restrict__ state, const float* __restrict__ pa,
        const float* __restrict__ pr, const float* __restrict__ ts,
        const float* __restrict__ cue, const float* __restrict__ K,
        const float* __restrict__ Wx, const float* __restrict__ Wh,
        const float* __restrict__ b, const float* __restrict__ h0,
        float* __restrict__ ws) {
    if (blockIdx.x == 0 && threadIdx.x == 0)
        ((int*)ws)[CNT_OFF] = 0;   // ticket for kernel B (stream-ordered: B after A)

    const int lane = threadIdx.x & 63;
    const int wib  = threadIdx.x >> 6;
    const int gw   = blockIdx.x * 4 + wib;
    const int nw   = NBLK_A * 4;                 // 8192 waves

    // ---- preact rows (first 2560 waves; hides under the BW-bound sweep) ----
    if (gw < 5 * HDIM) {
        const int row = gw;
        float x0 = state[lane];
        float x1 = 0.f;
        if      (lane < 4)  x1 = pa[lane];
        else if (lane == 4) x1 = pr[0];
        else if (lane == 5) x1 = ts[0];

        const float4* h04 = (const float4*)h0;
        const float4  hA = h04[lane], hB = h04[64 + lane];
        const float4* wh4 = (const float4*)(Wh + (size_t)row * HDIM);
        const float4 a0 = wh4[lane], a1 = wh4[64 + lane];
        float acc = a0.x*hA.x + a0.y*hA.y + a0.z*hA.z + a0.w*hA.w
                  + a1.x*hB.x + a1.y*hB.y + a1.z*hB.z + a1.w*hB.w;
        const float* wxr = Wx + (size_t)row * 70;
        acc += wxr[lane] * x0;
        if (lane < 6) acc += wxr[64 + lane] * x1;
        acc = wave_sum(acc);
        if (lane == 0) ws[PREACT_OFF + row] = acc + b[row];
    }

    // ---- sims sweep: 4-row groups, 8 dwordx4 loads in flight, ILP'd reduce --
    const float4* c4 = (const float4*)cue;
    const float4 cA = c4[lane], cB = c4[64 + lane];
    float minss = INFINITY;

    const int NG = NROWS / 4;                    // 25000 groups (NROWS % 4 == 0)
    for (int g = gw; g < NG; g += nw) {
        const int n = g * 4;                     // rows n..n+3
        const float* r = K + (size_t)n * HDIM;
        const float4* p0 = (const float4*)(r);
        const float4* p1 = (const float4*)(r + HDIM);
        const float4* p2 = (const float4*)(r + 2 * HDIM);
        const float4* p3 = (const float4*)(r + 3 * HDIM);
        const float4 a0 = p0[lane], b0 = p0[64 + lane];
        const float4 a1 = p1[lane], b1 = p1[64 + lane];
        const float4 a2 = p2[lane], b2 = p2[64 + lane];
        const float4 a3 = p3[lane], b3 = p3[64 + lane];
        float s0 = d2sum(a0, cA) + d2sum(b0, cB);
        float s1 = d2sum(a1, cA) + d2sum(b1, cB);
        float s2 = d2sum(a2, cA) + d2sum(b2, cB);
        float s3 = d2sum(a3, cA) + d2sum(b3, cB);
        #pragma unroll
        for (int off = 32; off; off >>= 1) {     // 4 independent chains, ILP
            s0 += __shfl_xor(s0, off);
            s1 += __shfl_xor(s1, off);
            s2 += __shfl_xor(s2, off);
            s3 += __shfl_xor(s3, off);
        }
        if (lane == 0) {                         // n%4==0 -> 16B aligned
            *(float4*)&ws[SIMS_OFF + n] = make_float4(-s0, -s1, -s2, -s3);
        }
        minss = fminf(fminf(minss, s0), fminf(fminf(s1, s2), s3));
    }

    minss = wave_min(minss);
    __shared__ float smin[4];
    if (lane == 0) smin[wib] = minss;
    __syncthreads();
    if (threadIdx.x == 0)
        ws[BMIN_OFF + blockIdx.x] =
            fminf(fminf(smin[0], smin[1]), fminf(smin[2], smin[3]));
}

// ====== kernel B: 1024-thread blocks (16 waves) — latency-tolerant scan ======
__global__ __launch_bounds__(TB_B)
void kB(const float* __restrict__ V, const float* __restrict__ c0,
        const float* __restrict__ aw, const float* __restrict__ ab,
        const float* __restrict__ cw, const float* __restrict__ cb,
        float* __restrict__ ws, float* __restrict__ out) {
    const int t    = threadIdx.x;                // 0..1023
    const int lane = t & 63;
    const int wib  = t >> 6;                     // 0..15

    // ---- global max: every block identical (deterministic) ----
    float mn = fminf(ws[BMIN_OFF + t], ws[BMIN_OFF + TB_B + t]);  // 2048 bmins
    mn = wave_min(mn);
    __shared__ float sred[16];
    if (lane == 0) sred[wib] = mn;
    __syncthreads();
    float gmn = sred[0];
    #pragma unroll
    for (int w = 1; w < 16; w++) gmn = fminf(gmn, sred[w]);
    const float smax = -gmn;

    // ---- scan sims: 1024 waves total, <=2 chunk iterations per wave ----
    const int gwid = blockIdx.x * 16 + wib;      // 0..1023
    float4 accA = {0.f,0.f,0.f,0.f}, accB = {0.f,0.f,0.f,0.f};
    float dsum = 0.f;

    const int nchunks = (NROWS + 63) / 64;       // 1563
    for (int c = gwid; c < nchunks; c += NBLK_B * 16) {
        const int n = c * 64 + lane;
        const bool valid = (n < NROWS);
        const float s = valid ? ws[SIMS_OFF + n] : -INFINITY;
        const float e = expf(s - smax);          // underflows to 0 for far rows
        dsum += e;                                // exact denominator
        unsigned long long mask = __ballot(valid && (s - smax >= -30.0f));
        while (mask) {
            const int bpos = __ffsll(mask) - 1;
            mask &= mask - 1;
            const int nb = c * 64 + bpos;
            const float eb = __shfl(e, bpos);
            const float4* v4 = (const float4*)(V + (size_t)nb * HDIM);
            const float4 vA = v4[lane], vB = v4[64 + lane];
            accA.x += eb * vA.x; accA.y += eb * vA.y;
            accA.z += eb * vA.z; accA.w += eb * vA.w;
            accB.x += eb * vB.x; accB.y += eb * vB.y;
            accB.z += eb * vB.z; accB.w += eb * vB.w;
        }
    }
    dsum = wave_sum(dsum);

    __shared__ float lm[16][HDIM];               // 32 KB
    __shared__ float ld[16];
    {
        float* rowp = lm[wib];
        rowp[lane*4 + 0]       = accA.x; rowp[lane*4 + 1]       = accA.y;
        rowp[lane*4 + 2]       = accA.z; rowp[lane*4 + 3]       = accA.w;
        rowp[256 + lane*4 + 0] = accB.x; rowp[256 + lane*4 + 1] = accB.y;
        rowp[256 + lane*4 + 2] = accB.z; rowp[256 + lane*4 + 3] = accB.w;
        if (lane == 0) ld[wib] = dsum;
    }
    __syncthreads();

    if (t < HDIM) {
        float s = 0.f;
        #pragma unroll
        for (int w = 0; w < 16; w++) s += lm[w][t];
        ws[PM_OFF + blockIdx.x * HDIM + t] = s;
    }
    if (t == 0) {
        float d = 0.f;
        #pragma unroll
        for (int w = 0; w < 16; w++) d += ld[w];
        ws[PD_OFF + blockIdx.x] = d;
    }

    // ---- ticket: last block to finish does the final (no polling) ----
    __threadfence();                              // release partials
    __shared__ int sOld;
    if (t == 0) sOld = atomicAdd((int*)ws + CNT_OFF, 1);
    __syncthreads();
    if (sOld != NBLK_B - 1) return;
    __threadfence();                              // acquire others' partials

    __shared__ float hl[HDIM];
    __shared__ float sden;
    __shared__ float logits[4];

    if (t < 64) {                                 // wave 0: denominator
        float d = ws[PD_OFF + t];
        d = wave_sum(d);
        if (t == 0) sden = d;
    }
    float m = 0.f;
    if (t < HDIM) {
        #pragma unroll 8
        for (int b2 = 0; b2 < NBLK_B; b2++) m += ws[PM_OFF + b2 * HDIM + t];
    }
    __syncthreads();

    if (t < HDIM) {
        m /= sden;
        const float pf = ws[PREACT_OFF + t];
        const float pi = ws[PREACT_OFF + HDIM + t];
        const float po = ws[PREACT_OFF + 2*HDIM + t];
        const float prg= ws[PREACT_OFF + 3*HDIM + t];
        const float pc = ws[PREACT_OFF + 4*HDIM + t];
        const float f_t = 1.f / (1.f + expf(-pf));
        const float i_t = 1.f / (1.f + expf(-pi));
        const float o_t = 1.f / (1.f + expf(-po));
        const float r_t = 1.f / (1.f + expf(-prg));
        const float chat = tanhf(pc);
        const float ct = f_t * c0[t] + i_t * chat + r_t * m;
        const float ht = o_t * tanhf(ct);
        out[517 + t] = ct;
        out[5 + t]   = ht;
        hl[t] = ht;
    }
    __syncthreads();

    if (wib < 4) {       // actor logits, one wave per row
        float acc = 0.f;
        #pragma unroll
        for (int j = 0; j < HDIM; j += 64)
            acc += aw[wib * HDIM + j + lane] * hl[j + lane];
        acc = wave_sum(acc);
        if (lane == 0) logits[wib] = acc + ab[wib];
    }
    if (wib == 4) {      // critic
        float acc = 0.f;
        #pragma unroll
        for (int j = 0; j < HDIM; j += 64)
            acc += cw[j + lane] * hl[j + lane];
        acc = wave_sum(acc);
        if (lane == 0) out[4] = acc + cb[0];
    }
    __syncthreads();

    if (t == 0) {
        const float mx = fmaxf(fmaxf(logits[0], logits[1]),
                               fmaxf(logits[2], logits[3]));
        const float e0 = expf(logits[0] - mx), e1 = expf(logits[1] - mx);
        const float e2 = expf(logits[2] - mx), e3 = expf(logits[3] - mx);
        const float inv = 1.f / (e0 + e1 + e2 + e3);
        out[0] = e0 * inv; out[1] = e1 * inv;
        out[2] = e2 * inv; out[3] = e3 * inv;
    }
}

extern "C" void kernel_launch(void* const* d_in, const int* in_sizes, int n_in,
                              void* d_out, int out_size, void* d_ws, size_t ws_size,
                              hipStream_t stream) {
    const float* state  = (const float*)d_in[0];
    const float* pa     = (const float*)d_in[1];
    const float* pr     = (const float*)d_in[2];
    const float* ts     = (const float*)d_in[3];
    const float* cue    = (const float*)d_in[4];
    const float* keys   = (const float*)d_in[5];
    const float* vals   = (const float*)d_in[6];
    const float* Wx     = (const float*)d_in[7];
    const float* Wh     = (const float*)d_in[8];
    const float* b      = (const float*)d_in[9];
    const float* aw     = (const float*)d_in[10];
    const float* ab     = (const float*)d_in[11];
    const float* cw     = (const float*)d_in[12];
    const float* cb     = (const float*)d_in[13];
    const float* h0     = (const float*)d_in[14];
    const float* c0     = (const float*)d_in[15];
    float* ws  = (float*)d_ws;
    float* out = (float*)d_out;

    kA<<<NBLK_A, 256, 0, stream>>>(state, pa, pr, ts, cue, keys, Wx, Wh, b, h0, ws);
    kB<<<NBLK_B, TB_B, 0, stream>>>(vals, c0, aw, ab, cw, cb, ws, out);
}

// Round 10
// 54.568 us; speedup vs baseline: 1.6410x; 1.2250x over previous
//
#include <hip/hip_runtime.h>
#include <math.h>

#define HDIM 512
#define NROWS 100000
#define NBLK_A 2048
#define K_CAP 1024           // max survivors kB holds (data: ~3)

// ---- workspace layout (float indices) ----
constexpr int SIMS_OFF   = 0;                        // [NROWS] sims = -||K-cue||^2 (write-only legacy path)
constexpr int BMIN_OFF   = NROWS;                    // [NBLK_A] per-block min ||K-cue||^2
constexpr int CNTL_OFF   = BMIN_OFF + NBLK_A;        // [NBLK_A] int candidate counts
constexpr int CAND_OFF   = CNTL_OFF + NBLK_A;        // [NBLK_A*64] float2 {ss, idx}
constexpr int PREACT_OFF = CAND_OFF + NBLK_A * 128;  // [5*HDIM]

__device__ __forceinline__ float wave_sum(float v) {
    #pragma unroll
    for (int off = 32; off; off >>= 1) v += __shfl_xor(v, off);
    return v;
}
__device__ __forceinline__ float wave_min(float v) {
    #pragma unroll
    for (int off = 32; off; off >>= 1) v = fminf(v, __shfl_xor(v, off));
    return v;
}
__device__ __forceinline__ float d2sum(float4 a, float4 c) {
    float d, s;
    d = a.x - c.x; s  = d * d;
    d = a.y - c.y; s += d * d;
    d = a.z - c.z; s += d * d;
    d = a.w - c.w; s += d * d;
    return s;
}

// ===== kernel A: R4 hot loop (roofline) + register-held candidate emission ===
__global__ __launch_bounds__(256)
void kA(const float* __restrict__ state, const float* __restrict__ pa,
        const float* __restrict__ pr, const float* __restrict__ ts,
        const float* __restrict__ cue, const float* __restrict__ K,
        const float* __restrict__ Wx, const float* __restrict__ Wh,
        const float* __restrict__ b, const float* __restrict__ h0,
        float* __restrict__ ws) {
    const int lane = threadIdx.x & 63;
    const int wib  = threadIdx.x >> 6;
    const int gw   = blockIdx.x * 4 + wib;
    const int nw   = NBLK_A * 4;                 // 8192 waves

    // ---- preact rows (first 2560 waves; hides under the BW-bound sweep) ----
    if (gw < 5 * HDIM) {
        const int row = gw;
        float x0 = state[lane];
        float x1 = 0.f;
        if      (lane < 4)  x1 = pa[lane];
        else if (lane == 4) x1 = pr[0];
        else if (lane == 5) x1 = ts[0];

        const float4* h04 = (const float4*)h0;
        const float4  hA = h04[lane], hB = h04[64 + lane];
        const float4* wh4 = (const float4*)(Wh + (size_t)row * HDIM);
        const float4 a0 = wh4[lane], a1 = wh4[64 + lane];
        float acc = a0.x*hA.x + a0.y*hA.y + a0.z*hA.z + a0.w*hA.w
                  + a1.x*hB.x + a1.y*hB.y + a1.z*hB.z + a1.w*hB.w;
        const float* wxr = Wx + (size_t)row * 70;
        acc += wxr[lane] * x0;
        if (lane < 6) acc += wxr[64 + lane] * x1;
        acc = wave_sum(acc);
        if (lane == 0) ws[PREACT_OFF + row] = acc + b[row];
    }

    // ---- sims sweep: IDENTICAL memory path to round 4 ----
    const float4* c4 = (const float4*)cue;
    const float4 cA = c4[lane], cB = c4[64 + lane];
    float minss = INFINITY;

    const float4 inf4 = make_float4(INFINITY, INFINITY, INFINITY, INFINITY);
    float4 r0 = inf4, r1 = inf4, r2 = inf4, r3 = inf4;  // per-iter results (static idx)
    int it = 0;

    const int NG = NROWS / 4;                    // 25000 groups (NROWS % 4 == 0)
    for (int g = gw; g < NG; g += nw) {          // 3 or 4 iterations
        const int n = g * 4;                     // rows n..n+3
        const float* r = K + (size_t)n * HDIM;
        const float4* p0 = (const float4*)(r);
        const float4* p1 = (const float4*)(r + HDIM);
        const float4* p2 = (const float4*)(r + 2 * HDIM);
        const float4* p3 = (const float4*)(r + 3 * HDIM);
        const float4 a0 = p0[lane], b0 = p0[64 + lane];
        const float4 a1 = p1[lane], b1 = p1[64 + lane];
        const float4 a2 = p2[lane], b2 = p2[64 + lane];
        const float4 a3 = p3[lane], b3 = p3[64 + lane];
        float s0 = d2sum(a0, cA) + d2sum(b0, cB);
        float s1 = d2sum(a1, cA) + d2sum(b1, cB);
        float s2 = d2sum(a2, cA) + d2sum(b2, cB);
        float s3 = d2sum(a3, cA) + d2sum(b3, cB);
        #pragma unroll
        for (int off = 32; off; off >>= 1) {     // 4 independent chains, ILP
            s0 += __shfl_xor(s0, off);
            s1 += __shfl_xor(s1, off);
            s2 += __shfl_xor(s2, off);
            s3 += __shfl_xor(s3, off);
        }
        if (lane == 0) {                         // n%4==0 -> 16B aligned
            *(float4*)&ws[SIMS_OFF + n] = make_float4(-s0, -s1, -s2, -s3);
        }
        const float4 res = make_float4(s0, s1, s2, s3);
        if      (it == 0) r0 = res;              // static register save
        else if (it == 1) r1 = res;
        else if (it == 2) r2 = res;
        else              r3 = res;
        ++it;
        minss = fminf(fminf(minss, s0), fminf(fminf(s1, s2), s3));
    }

    minss = wave_min(minss);
    __shared__ float smin[4];
    __shared__ int   wcnt[4];
    if (lane == 0) smin[wib] = minss;
    __syncthreads();
    const float bminv = fminf(fminf(smin[0], smin[1]),
                              fminf(smin[2], smin[3]));
    if (threadIdx.x == 0) ws[BMIN_OFF + blockIdx.x] = bminv;
    const float thr = bminv + 30.0f;

    // ---- candidate emission from registers: lane l owns (iter=l>>2, slot=l&3)
    const int qi = lane >> 2, qj = lane & 3;
    const float4 rq = (qi == 0) ? r0 : (qi == 1) ? r1 : (qi == 2) ? r2 : r3;
    const float v  = (qj == 0) ? rq.x : (qj == 1) ? rq.y : (qj == 2) ? rq.z : rq.w;
    const bool valid = (lane < 16) && (gw + qi * nw < NG);
    const bool ok    = valid && (v <= thr);
    const unsigned long long mask = __ballot(ok);
    const int cnt = (int)__popcll(mask);
    if (lane == 0) wcnt[wib] = cnt;
    __syncthreads();
    int woff = 0;
    #pragma unroll
    for (int w = 0; w < 4; w++) if (w < wib) woff += wcnt[w];
    if (ok) {
        const int pos = (int)__popcll(mask & ((1ull << lane) - 1ull));
        const int row = (gw + qi * nw) * 4 + qj;
        float2* cand = (float2*)(ws + CAND_OFF);
        cand[(blockIdx.x << 6) + woff + pos] = make_float2(v, __int_as_float(row));
    }
    if (threadIdx.x == 0)
        ((int*)ws)[CNTL_OFF + blockIdx.x] = wcnt[0] + wcnt[1] + wcnt[2] + wcnt[3];
}

// ===== kernel B: ONE 1024-thread block — candidates only (~70 KB total) =====
__global__ __launch_bounds__(1024)
void kB(const float* __restrict__ V, const float* __restrict__ c0,
        const float* __restrict__ aw, const float* __restrict__ ab,
        const float* __restrict__ cw, const float* __restrict__ cb,
        float* __restrict__ ws, float* __restrict__ out) {
    const int t    = threadIdx.x;                // 0..1023
    const int lane = t & 63;
    const int wib  = t >> 6;                     // 0..15

    __shared__ float sred[16];
    __shared__ int   wtot[16];
    __shared__ int   stot;
    __shared__ float surv_s[K_CAP];
    __shared__ int   surv_n[K_CAP];
    __shared__ float sden;
    __shared__ float hl[HDIM];
    __shared__ float logits[4];

    // ---- 1) global min over 2048 block-mins ----
    float mn = fminf(ws[BMIN_OFF + t], ws[BMIN_OFF + 1024 + t]);
    mn = wave_min(mn);
    if (lane == 0) sred[wib] = mn;
    __syncthreads();
    float smin = sred[0];
    #pragma unroll
    for (int w = 1; w < 16; w++) smin = fminf(smin, sred[w]);
    const float thr = smin + 30.0f;

    // ---- 2) survivor compaction (two-pass, thread-ordered, deterministic) ---
    const int*    cnts = (const int*)ws + CNTL_OFF;
    const float2* cand = (const float2*)(ws + CAND_OFF);

    int mycnt = 0;
    #pragma unroll
    for (int L = 0; L < 2; L++) {                // lists 2t, 2t+1
        const int bidx = 2 * t + L;
        const int c = cnts[bidx];
        for (int e = 0; e < c; e++)
            if (cand[(bidx << 6) + e].x <= thr) mycnt++;
    }
    int inc = mycnt;                             // wave inclusive scan
    #pragma unroll
    for (int off = 1; off < 64; off <<= 1) {
        const int v = __shfl_up(inc, off);
        if (lane >= off) inc += v;
    }
    if (lane == 63) wtot[wib] = inc;
    __syncthreads();
    int base = 0;
    #pragma unroll
    for (int w = 0; w < 16; w++) if (w < wib) base += wtot[w];
    int off = base + inc - mycnt;                // exclusive offset
    #pragma unroll
    for (int L = 0; L < 2; L++) {                // pass 2: identical order
        const int bidx = 2 * t + L;
        const int c = cnts[bidx];
        for (int e = 0; e < c; e++) {
            const float2 ce = cand[(bidx << 6) + e];
            if (ce.x <= thr) {
                if (off < K_CAP) {
                    surv_s[off] = ce.x;
                    surv_n[off] = __float_as_int(ce.y);
                }
                off++;
            }
        }
    }
    if (t == 1023) stot = off;                   // total survivors
    __syncthreads();
    const int tot = (stot < K_CAP) ? stot : K_CAP;

    // ---- 3) weights + exact denominator (serial, deterministic order) ----
    if (t == 0) {
        float den = 0.f;
        for (int i = 0; i < tot; i++) {
            const float e = expf(smin - surv_s[i]);  // = exp(sim - smax)
            surv_s[i] = e;
            den += e;
        }
        sden = den;
    }
    __syncthreads();
    const float inv_den = 1.f / sden;

    // ---- 4) m_t + LSTM cell (threads 0..511, one per dim) ----
    if (t < HDIM) {
        float m = 0.f;
        for (int i = 0; i < tot; i++)
            m += surv_s[i] * V[(size_t)surv_n[i] * HDIM + t];
        m *= inv_den;

        const float pf = ws[PREACT_OFF + t];
        const float pi = ws[PREACT_OFF + HDIM + t];
        const float po = ws[PREACT_OFF + 2*HDIM + t];
        const float prg= ws[PREACT_OFF + 3*HDIM + t];
        const float pc = ws[PREACT_OFF + 4*HDIM + t];
        const float f_t = 1.f / (1.f + expf(-pf));
        const float i_t = 1.f / (1.f + expf(-pi));
        const float o_t = 1.f / (1.f + expf(-po));
        const float r_t = 1.f / (1.f + expf(-prg));
        const float chat = tanhf(pc);
        const float ct = f_t * c0[t] + i_t * chat + r_t * m;
        const float ht = o_t * tanhf(ct);
        out[517 + t] = ct;
        out[5 + t]   = ht;
        hl[t] = ht;
    }
    __syncthreads();

    if (wib < 4) {       // actor logits, one wave per row
        float acc = 0.f;
        #pragma unroll
        for (int j = 0; j < HDIM; j += 64)
            acc += aw[wib * HDIM + j + lane] * hl[j + lane];
        acc = wave_sum(acc);
        if (lane == 0) logits[wib] = acc + ab[wib];
    }
    if (wib == 4) {      // critic
        float acc = 0.f;
        #pragma unroll
        for (int j = 0; j < HDIM; j += 64)
            acc += cw[j + lane] * hl[j + lane];
        acc = wave_sum(acc);
        if (lane == 0) out[4] = acc + cb[0];
    }
    __syncthreads();

    if (t == 0) {
        const float mx = fmaxf(fmaxf(logits[0], logits[1]),
                               fmaxf(logits[2], logits[3]));
        const float e0 = expf(logits[0] - mx), e1 = expf(logits[1] - mx);
        const float e2 = expf(logits[2] - mx), e3 = expf(logits[3] - mx);
        const float inv = 1.f / (e0 + e1 + e2 + e3);
        out[0] = e0 * inv; out[1] = e1 * inv;
        out[2] = e2 * inv; out[3] = e3 * inv;
    }
}

extern "C" void kernel_launch(void* const* d_in, const int* in_sizes, int n_in,
                              void* d_out, int out_size, void* d_ws, size_t ws_size,
                              hipStream_t stream) {
    const float* state  = (const float*)d_in[0];
    const float* pa     = (const float*)d_in[1];
    const float* pr     = (const float*)d_in[2];
    const float* ts     = (const float*)d_in[3];
    const float* cue    = (const float*)d_in[4];
    const float* keys   = (const float*)d_in[5];
    const float* vals   = (const float*)d_in[6];
    const float* Wx     = (const float*)d_in[7];
    const float* Wh     = (const float*)d_in[8];
    const float* b      = (const float*)d_in[9];
    const float* aw     = (const float*)d_in[10];
    const float* ab     = (const float*)d_in[11];
    const float* cw     = (const float*)d_in[12];
    const float* cb     = (const float*)d_in[13];
    const float* h0     = (const float*)d_in[14];
    const float* c0     = (const float*)d_in[15];
    float* ws  = (float*)d_ws;
    float* out = (float*)d_out;

    kA<<<NBLK_A, 256, 0, stream>>>(state, pa, pr, ts, cue, keys, Wx, Wh, b, h0, ws);
    kB<<<1, 1024, 0, stream>>>(vals, c0, aw, ab, cw, cb, ws, out);
}